// Round 12
// baseline (481.190 us; speedup 1.0000x reference)
//
#include <hip/hip_runtime.h>
#include <stdint.h>

#define LSEQ 1024
#define HDIM 1024
#define DDIM 2048
#define BL 2048
#define NST 16
#define XR 1027          // 3 halo rows + 1024 tokens

typedef unsigned short u16;
typedef __attribute__((ext_vector_type(8))) short bf16x8;
typedef __attribute__((ext_vector_type(4))) float f32x4;

static __device__ __forceinline__ float silu_f(float v) { return v / (1.f + __expf(-v)); }
static __device__ __forceinline__ float bf2f(u16 u) {
  union { float f; unsigned int i; } c; c.i = ((unsigned int)u) << 16; return c.f;
}
static __device__ __forceinline__ u16 f2bf(float f) {
  union { float f; unsigned int i; } c; c.f = f;
  unsigned int r = c.i + 0x7fffu + ((c.i >> 16) & 1u);
  return (u16)(r >> 16);
}

// ---------------- cast fp32 -> bf16 (weights, once per launch) ----------------
__global__ __launch_bounds__(256) void k_castw(const float* __restrict__ src,
                                               u16* __restrict__ dst) {
  int idx = blockIdx.x * 256 + threadIdx.x;
  float4 v = ((const float4*)src)[idx];
  ushort4 o;
  o.x = f2bf(v.x); o.y = f2bf(v.y); o.z = f2bf(v.z); o.w = f2bf(v.w);
  ((ushort4*)dst)[idx] = o;
}

// ---------------- per-row rmsnorm scale ----------------
__global__ __launch_bounds__(256) void k_rowscale(const float* __restrict__ inp,
                                                  float* __restrict__ rs) {
  int row = blockIdx.x;
  int t = threadIdx.x;
  float4 xv = *(const float4*)(inp + (size_t)row * HDIM + t * 4);
  float ss = xv.x * xv.x + xv.y * xv.y + xv.z * xv.z + xv.w * xv.w;
  for (int off = 32; off > 0; off >>= 1) ss += __shfl_down(ss, off);
  __shared__ float red[4];
  if ((t & 63) == 0) red[t >> 6] = ss;
  __syncthreads();
  if (t == 0) {
    float tot = red[0] + red[1] + red[2] + red[3];
    rs[row] = rsqrtf(tot * (1.f / HDIM) + 1e-6f);
  }
}

// ---------------- K1: in_proj MFMA GEMM, rmsnorm fused into A staging ----------------
__global__ __launch_bounds__(256) void k_gemm1_mfma(const float* __restrict__ inp,
                                                    const u16* __restrict__ W,
                                                    const float* __restrict__ bias,
                                                    const float* __restrict__ rscale,
                                                    const float* __restrict__ nw,
                                                    u16* __restrict__ xgb) {
  __shared__ u16 Asm[64 * 40];
  __shared__ u16 Wsm[64 * 40];
  int t = threadIdx.x;
  int m0 = blockIdx.y * 64, n0 = blockIdx.x * 64;
  int srow = t >> 2, koff = (t & 3) * 8;
  int gin = m0 + srow;
  const float* Ag = inp + (size_t)gin * HDIM + koff;
  const u16* Wg = W + (size_t)(n0 + srow) * HDIM + koff;
  float scale = rscale[gin];
  int w = t >> 6, lane = t & 63;
  int quad = lane >> 4, mr = lane & 15;
  f32x4 z = {0.f, 0.f, 0.f, 0.f};
  f32x4 acc0 = z, acc1 = z, acc2 = z, acc3 = z;
  const u16* arp = &Asm[(16 * w + mr) * 40 + quad * 8];
  const u16* brp = &Wsm[mr * 40 + quad * 8];
  for (int k0 = 0; k0 < HDIM; k0 += 32) {
    float4 a0 = *(const float4*)(Ag + k0);
    float4 a1 = *(const float4*)(Ag + k0 + 4);
    float4 n0v = *(const float4*)(nw + k0 + koff);
    float4 n1v = *(const float4*)(nw + k0 + koff + 4);
    uint4 wv = *(const uint4*)(Wg + k0);
    ushort4 p0, p1;
    p0.x = f2bf(a0.x * scale * n0v.x); p0.y = f2bf(a0.y * scale * n0v.y);
    p0.z = f2bf(a0.z * scale * n0v.z); p0.w = f2bf(a0.w * scale * n0v.w);
    p1.x = f2bf(a1.x * scale * n1v.x); p1.y = f2bf(a1.y * scale * n1v.y);
    p1.z = f2bf(a1.z * scale * n1v.z); p1.w = f2bf(a1.w * scale * n1v.w);
    __syncthreads();
    *(ushort4*)(&Asm[srow * 40 + koff]) = p0;
    *(ushort4*)(&Asm[srow * 40 + koff + 4]) = p1;
    *(uint4*)(&Wsm[srow * 40 + koff]) = wv;
    __syncthreads();
    bf16x8 af = *(const bf16x8*)arp;
    bf16x8 b0 = *(const bf16x8*)(brp);
    bf16x8 b1 = *(const bf16x8*)(brp + 16 * 40);
    bf16x8 b2 = *(const bf16x8*)(brp + 32 * 40);
    bf16x8 b3 = *(const bf16x8*)(brp + 48 * 40);
    acc0 = __builtin_amdgcn_mfma_f32_16x16x32_bf16(af, b0, acc0, 0, 0, 0);
    acc1 = __builtin_amdgcn_mfma_f32_16x16x32_bf16(af, b1, acc1, 0, 0, 0);
    acc2 = __builtin_amdgcn_mfma_f32_16x16x32_bf16(af, b2, acc2, 0, 0, 0);
    acc3 = __builtin_amdgcn_mfma_f32_16x16x32_bf16(af, b3, acc3, 0, 0, 0);
  }
  f32x4 accs[4] = {acc0, acc1, acc2, acc3};
#pragma unroll
  for (int i = 0; i < 4; i++) {
    int col = n0 + 16 * i + mr;
    float bv = bias[col];
#pragma unroll
    for (int rr2 = 0; rr2 < 4; rr2++) {
      int rr = m0 + 16 * w + quad * 4 + rr2;
      int row = (rr >> 10) * XR + 3 + (rr & 1023);
      xgb[(size_t)row * 4096 + col] = f2bf(accs[i][rr2] + bv);
    }
  }
}

// ---------------- K4: out_proj MFMA GEMM + bias + residual (fp32 out) ----------------
__global__ __launch_bounds__(256) void k_gemm2_mfma(const u16* __restrict__ A,
                                                    const u16* __restrict__ W,
                                                    const float* __restrict__ bias,
                                                    const float* __restrict__ resid,
                                                    float* __restrict__ out) {
  __shared__ u16 Asm[64 * 40];
  __shared__ u16 Wsm[64 * 40];
  int t = threadIdx.x;
  int m0 = blockIdx.y * 64, n0 = blockIdx.x * 64;
  int srow = t >> 2, koff = (t & 3) * 8;
  const u16* Ag = A + (size_t)(m0 + srow) * DDIM + koff;
  const u16* Wg = W + (size_t)(n0 + srow) * DDIM + koff;
  int w = t >> 6, lane = t & 63;
  int quad = lane >> 4, mr = lane & 15;
  f32x4 z = {0.f, 0.f, 0.f, 0.f};
  f32x4 acc0 = z, acc1 = z, acc2 = z, acc3 = z;
  const u16* arp = &Asm[(16 * w + mr) * 40 + quad * 8];
  const u16* brp = &Wsm[mr * 40 + quad * 8];
  for (int k0 = 0; k0 < DDIM; k0 += 32) {
    uint4 av = *(const uint4*)(Ag + k0);
    uint4 wv = *(const uint4*)(Wg + k0);
    __syncthreads();
    *(uint4*)(&Asm[srow * 40 + koff]) = av;
    *(uint4*)(&Wsm[srow * 40 + koff]) = wv;
    __syncthreads();
    bf16x8 af = *(const bf16x8*)arp;
    bf16x8 b0 = *(const bf16x8*)(brp);
    bf16x8 b1 = *(const bf16x8*)(brp + 16 * 40);
    bf16x8 b2 = *(const bf16x8*)(brp + 32 * 40);
    bf16x8 b3 = *(const bf16x8*)(brp + 48 * 40);
    acc0 = __builtin_amdgcn_mfma_f32_16x16x32_bf16(af, b0, acc0, 0, 0, 0);
    acc1 = __builtin_amdgcn_mfma_f32_16x16x32_bf16(af, b1, acc1, 0, 0, 0);
    acc2 = __builtin_amdgcn_mfma_f32_16x16x32_bf16(af, b2, acc2, 0, 0, 0);
    acc3 = __builtin_amdgcn_mfma_f32_16x16x32_bf16(af, b3, acc3, 0, 0, 0);
  }
  f32x4 accs[4] = {acc0, acc1, acc2, acc3};
#pragma unroll
  for (int i = 0; i < 4; i++) {
    int col = n0 + 16 * i + mr;
    float bv = bias[col];
#pragma unroll
    for (int rr2 = 0; rr2 < 4; rr2++) {
      int gout = m0 + 16 * w + quad * 4 + rr2;
      out[(size_t)gout * HDIM + col] =
          accs[i][rr2] + bv + resid[(size_t)gout * HDIM + col];
    }
  }
}

// ---------------- K2: conv+silu (LDS) then x_proj; token-major proj[BL][96] ----------------
__global__ __launch_bounds__(256) void k_xprojc(const u16* __restrict__ xgb,
                                                const float* __restrict__ cw,
                                                const float* __restrict__ cb,
                                                const float* __restrict__ w,
                                                const float* __restrict__ b,
                                                float* __restrict__ proj) {
  __shared__ float row[DDIM];
  int bb = blockIdx.x >> 10, l = blockIdx.x & 1023;
  int t = threadIdx.x;
  int d = t * 8;
  float acc[8];
#pragma unroll
  for (int i = 0; i < 8; i++) acc[i] = cb[d + i];
  float cwv[8][4];
#pragma unroll
  for (int i = 0; i < 8; i++) {
    float4 v = *(const float4*)(cw + (d + i) * 4);
    cwv[i][0] = v.x; cwv[i][1] = v.y; cwv[i][2] = v.z; cwv[i][3] = v.w;
  }
#pragma unroll
  for (int j = 0; j < 4; j++) {
    if (l - 3 + j >= 0) {
      const u16* xr = xgb + (size_t)(bb * XR + l + j) * 4096 + d;
      ushort4 v0 = *(const ushort4*)xr;
      ushort4 v1 = *(const ushort4*)(xr + 4);
      acc[0] += bf2f(v0.x) * cwv[0][j]; acc[1] += bf2f(v0.y) * cwv[1][j];
      acc[2] += bf2f(v0.z) * cwv[2][j]; acc[3] += bf2f(v0.w) * cwv[3][j];
      acc[4] += bf2f(v1.x) * cwv[4][j]; acc[5] += bf2f(v1.y) * cwv[5][j];
      acc[6] += bf2f(v1.z) * cwv[6][j]; acc[7] += bf2f(v1.w) * cwv[7][j];
    }
  }
#pragma unroll
  for (int i = 0; i < 8; i++) row[d + i] = silu_f(acc[i]);
  __syncthreads();
  int wv = t >> 6, lane = t & 63;
  const float4* row4 = (const float4*)row;
  int tk = (bb << 10) + l;
  for (int o = wv; o < 96; o += 4) {
    const float4* wr4 = (const float4*)(w + (size_t)o * DDIM);
    float s0 = 0.f, s1 = 0.f, s2 = 0.f, s3 = 0.f;
#pragma unroll
    for (int k4 = 0; k4 < 8; k4++) {
      int idx = (k4 << 6) + lane;
      float4 wv4 = wr4[idx];
      float4 rv4 = row4[idx];
      s0 += rv4.x * wv4.x; s1 += rv4.y * wv4.y;
      s2 += rv4.z * wv4.z; s3 += rv4.w * wv4.w;
    }
    float s = (s0 + s1) + (s2 + s3);
    s += __shfl_xor(s, 32); s += __shfl_xor(s, 16);
    s += __shfl_xor(s, 8);  s += __shfl_xor(s, 4);
    s += __shfl_xor(s, 2);  s += __shfl_xor(s, 1);
    if (lane == 0) proj[(size_t)tk * 96 + o] = s + b[o];
  }
}

// ---------------- K2b: transpose proj[BL][96] -> projT[96][BL] ----------------
__global__ __launch_bounds__(256) void k_transpose(const float* __restrict__ proj,
                                                   float* __restrict__ projT) {
  __shared__ float tile[64][97];
  int blk = blockIdx.x;
  int b = blk >> 4;
  int tok0 = (b << 10) + (blk & 15) * 64;
  int t = threadIdx.x;
  const float* src = proj + (size_t)tok0 * 96;
#pragma unroll
  for (int i = 0; i < 24; i++) {
    int idx = t + i * 256;
    int row = idx / 96, col = idx - row * 96;
    tile[row][col] = src[idx];
  }
  __syncthreads();
  int wv = t >> 6, lane = t & 63;
#pragma unroll
  for (int i = 0; i < 24; i++) {
    int o = wv + i * 4;
    projT[(size_t)o * BL + tok0 + lane] = tile[lane][o];
  }
}

// ---------------- K3: full-sequence scan; lane owns 4 consecutive tokens ----------------
__global__ __launch_bounds__(256) void k_scan(const float* __restrict__ projT,
                                              const u16* __restrict__ xgb,
                                              const float* __restrict__ cw,
                                              const float* __restrict__ cb,
                                              const float* __restrict__ dtw,
                                              const float* __restrict__ dtb,
                                              const float* __restrict__ alog,
                                              const float* __restrict__ dparam,
                                              const float* __restrict__ cs,
                                              u16* __restrict__ yb) {
  __shared__ float xs[259];
  __shared__ float xcs[256];
  __shared__ float ds_s[256];
  __shared__ float Dl[256];
  __shared__ float dtw_s[64];
  __shared__ float wtot[4];
  __shared__ float ys[4][256];

  int t = threadIdx.x;
  int cidx = ((blockIdx.x & 7) << 9) | (blockIdx.x >> 3);   // XCD swizzle
  int b = cidx >> 11;
  int d = cidx & (DDIM - 1);
  int wv = t >> 6, lane = t & 63;
  int tok0 = lane << 2;                 // 4 consecutive tokens per lane (segment-local)

  if (t < 64) dtw_s[t] = dtw[(size_t)d * 64 + t];
  float4 cwv = *(const float4*)(cw + d * 4);
  float cbv = cb[d];
  float dtbv = dtb[d];
  float Dp = dparam[d];
  float An[4], state[4], Soff[4];
#pragma unroll
  for (int r = 0; r < 4; r++) {
    int n = wv * 4 + r;
    An[r] = -__expf(alog[d * NST + n]);
    state[r] = cs[(size_t)(b * DDIM + d) * NST + n];
    Soff[r] = 0.f;
  }
  float Dc = 0.f;
  const u16* xcol = xgb + (size_t)(b * XR + 3) * 4096 + d;
  const u16* gcol = xcol + DDIM;
  u16* ycol = yb + (size_t)(b << 10) * DDIM + d;

  for (int seg = 0; seg < 4; seg++) {
    int base = seg << 8;
    int colT = (b << 10) + base;
    // stage x tokens [base-3, base+255]
    {
      int tok = base - 3 + t;
      xs[t] = (tok < 0) ? 0.f : bf2f(xcol[(size_t)tok * 4096]);
      if (t < 3) xs[256 + t] = bf2f(xcol[(size_t)(base + 253 + t) * 4096]);
    }
    __syncthreads();
    // conv + silu (thread t <-> token t)
    xcs[t] = silu_f(cbv + cwv.w * xs[t + 3] + cwv.z * xs[t + 2] + cwv.y * xs[t + 1] + cwv.x * xs[t]);
    // delta: 64-dot over projT rows (coalesced) + softplus
    float dval;
    {
      float acc = dtbv;
#pragma unroll
      for (int k = 0; k < 64; k++) acc += projT[(size_t)k * BL + colT + t] * dtw_s[k];
      dval = (acc > 20.f) ? acc : log1pf(__expf(acc));
      ds_s[t] = dval;
    }
    // prefix sum of delta (wave scan + cross-wave offsets)
    {
      float val = dval;
#pragma unroll
      for (int off = 1; off < 64; off <<= 1) {
        float u = __shfl_up(val, off);
        if (lane >= off) val += u;
      }
      if (lane == 63) wtot[wv] = val;
      __syncthreads();
      float woff = 0.f;
#pragma unroll
      for (int i = 0; i < 3; i++) if (i < wv) woff += wtot[i];
      Dl[t] = val + woff;
      __syncthreads();
    }
    float DlLast = Dl[255];
    float AnDc[4];
#pragma unroll
    for (int r = 0; r < 4; r++) AnDc[r] = An[r] * Dc;

    // main scan: lane owns tokens tok0..tok0+3; one wave-scan per r
    float4 Di = *(const float4*)&Dl[tok0];
    float De0 = (tok0 == 0) ? 0.f : Dl[tok0 - 1];
    float4 dsv = *(const float4*)&ds_s[tok0];
    float4 xcv = *(const float4*)&xcs[tok0];
    float4 yacc = {0.f, 0.f, 0.f, 0.f};
#pragma unroll
    for (int r = 0; r < 4; r++) {
      int n = wv * 4 + r;
      float4 Bv = *(const float4*)&projT[(size_t)(64 + n) * BL + colT + tok0];
      float4 Cv = *(const float4*)&projT[(size_t)(80 + n) * BL + colT + tok0];
      float P0 = __expf(AnDc[r] + An[r] * Di.x);
      float P1 = __expf(AnDc[r] + An[r] * Di.y);
      float P2 = __expf(AnDc[r] + An[r] * Di.z);
      float P3 = __expf(AnDc[r] + An[r] * Di.w);
      float Pp0 = __expf(AnDc[r] + An[r] * De0);
      float w0 = (dsv.x * Bv.x * xcv.x) / fmaxf(Pp0, 1e-10f);
      float w1 = (dsv.y * Bv.y * xcv.y) / fmaxf(P0, 1e-10f);
      float w2 = (dsv.z * Bv.z * xcv.z) / fmaxf(P1, 1e-10f);
      float w3 = (dsv.w * Bv.w * xcv.w) / fmaxf(P2, 1e-10f);
      float c0 = w0, c1 = c0 + w1, c2 = c1 + w2, c3 = c2 + w3;
      // wave inclusive scan of per-lane totals c3
      float T = c3;
#pragma unroll
      for (int off = 1; off < 64; off <<= 1) {
        float u = __shfl_up(T, off);
        if (lane >= off) T += u;
      }
      float excl = Soff[r] + T - c3;
      float S0 = excl + c0, S1 = excl + c1, S2 = excl + c2, S3 = excl + c3;
      yacc.x += (S0 * Pp0 + state[r] * P0) * Cv.x;
      yacc.y += (S1 * P0 + state[r] * P1) * Cv.y;
      yacc.z += (S2 * P1 + state[r] * P2) * Cv.z;
      yacc.w += (S3 * P2 + state[r] * P3) * Cv.w;
      Soff[r] += __shfl(T, 63);
    }
    *(float4*)&ys[wv][tok0] = yacc;
    __syncthreads();
    // y = wave-sum + D-term, gate, write bf16 (thread t <-> token t)
    {
      float y = ys[0][t] + ys[1][t] + ys[2][t] + ys[3][t] + xcs[t] * Dp;
      float g = bf2f(gcol[(size_t)(base + t) * 4096]);
      ycol[(size_t)(base + t) * DDIM] = f2bf(y * silu_f(g));
    }
    Dc += DlLast;
    __syncthreads();
  }
}

extern "C" void kernel_launch(void* const* d_in, const int* in_sizes, int n_in,
                              void* d_out, int out_size, void* d_ws, size_t ws_size,
                              hipStream_t stream) {
  const float* inp    = (const float*)d_in[0];
  const float* cstate = (const float*)d_in[1];
  const float* norm_w = (const float*)d_in[2];
  const float* w1     = (const float*)d_in[3];
  const float* b1     = (const float*)d_in[4];
  const float* convw  = (const float*)d_in[5];
  const float* convb  = (const float*)d_in[6];
  const float* xpw    = (const float*)d_in[7];
  const float* xpb    = (const float*)d_in[8];
  const float* dtw    = (const float*)d_in[9];
  const float* dtb    = (const float*)d_in[10];
  const float* alog   = (const float*)d_in[11];
  const float* dparam = (const float*)d_in[12];
  const float* wo     = (const float*)d_in[13];
  const float* bo     = (const float*)d_in[14];
  float* out = (float*)d_out;

  // workspace layout, 39,378,944 B total
  char* wsb = (char*)d_ws;
  u16*   w1b    = (u16*)(wsb + 0);            //  8,388,608 B  [4096][1024] bf16
  u16*   wob    = (u16*)(wsb + 8388608);      //  4,194,304 B  [1024][2048] bf16
  float* rscale = (float*)(wsb + 12582912);   //      8,192 B  [2048]
  float* proj   = (float*)(wsb + 12591104);   //    786,432 B  [2048][96] token-major
  float* projT  = (float*)(wsb + 13377536);   //    786,432 B  [96][2048] transposed
  u16*   xgb    = (u16*)(wsb + 14163968);     // 16,826,368 B  [2][1027][4096] bf16
  u16*   yb     = (u16*)(wsb + 30990336);     //  8,388,608 B  [2][1024][2048] bf16

  k_castw<<<4096, 256, 0, stream>>>(w1, w1b);
  k_castw<<<2048, 256, 0, stream>>>(wo, wob);
  k_rowscale<<<BL, 256, 0, stream>>>(inp, rscale);
  k_gemm1_mfma<<<dim3(64, 32), 256, 0, stream>>>(inp, w1b, b1, rscale, norm_w, xgb);
  k_xprojc<<<BL, 256, 0, stream>>>(xgb, convw, convb, xpw, xpb, proj);
  k_transpose<<<32, 256, 0, stream>>>(proj, projT);
  k_scan<<<2 * DDIM, 256, 0, stream>>>(projT, xgb, convw, convb, dtw, dtb,
                                       alog, dparam, cstate, yb);
  k_gemm2_mfma<<<dim3(16, 32), 256, 0, stream>>>(yb, wob, bo, inp, out);
}